// Round 1
// baseline (304.432 us; speedup 1.0000x reference)
//
#include <hip/hip_runtime.h>
#include <math.h>

// Mo3ENet neighbor selection: B=256, PER=1024, NIN=256, NOUT=768, K=32, R=6, BOX=32
// Outputs (concatenated, all written as float32):
//   [0)      src_ii  [B*NIN*K]
//   [E)      tgt     [B*NIN*K]
//   [2E)     m_ii    [B*NIN*K]
//   [3E)     dist_ii [B*NIN*K]
//   [4E)     src_io  [B*NIN*K]
//   [5E)     tgt     [B*NIN*K]
//   [6E)     m_io    [B*NIN*K]
//   [7E)     dist_io [B*NIN*K]

constexpr int BB    = 256;
constexpr int PERN  = 1024;
constexpr int NINC  = 256;
constexpr int NOUTC = 768;
constexpr int KK    = 32;
constexpr long EE   = (long)BB * NINC * KK;  // 2097152

__global__ __launch_bounds__(256) void mo3e_neigh_kernel(const float* __restrict__ pos,
                                                         float* __restrict__ out) {
#pragma clang fp contract(off)
    __shared__ float sp[PERN * 3];

    const int b   = blockIdx.x;
    const int tid = threadIdx.x;

    // Stage this batch's 1024 positions (12 KB) into LDS, coalesced.
    const float* gp = pos + (long)b * PERN * 3;
    for (int t = tid; t < PERN * 3; t += 256) sp[t] = gp[t];
    __syncthreads();

    const int i = tid;  // target index within batch (0..NIN-1)
    const float xi = sp[i * 3 + 0];
    const float yi = sp[i * 3 + 1];
    const float zi = sp[i * 3 + 2];

    const int  goff = b * PERN;
    const long e0   = ((long)(b * NINC + i)) * KK;

    float* __restrict__ o_src_ii = out;
    float* __restrict__ o_tgt_ii = out + EE;
    float* __restrict__ o_m_ii   = out + 2 * EE;
    float* __restrict__ o_d_ii   = out + 3 * EE;
    float* __restrict__ o_src_io = out + 4 * EE;
    float* __restrict__ o_tgt_io = out + 5 * EE;
    float* __restrict__ o_m_io   = out + 6 * EE;
    float* __restrict__ o_d_io   = out + 7 * EE;

    // Target column: constant per thread, same in both edge arrays.
    const float tv = (float)(goff + i);
    for (int k = 0; k < KK; ++k) {
        o_tgt_ii[e0 + k] = tv;
        o_tgt_io[e0 + k] = tv;
    }

    // ---------------- in-in ----------------
    // Predicate note: d2 < 36.0f is bit-identical to sqrtf(d2) < 6.0f for f32
    // (largest float below 36 has correctly-rounded sqrt strictly below 6).
    {
        int cnt = 0;
        for (int j = 0; j < NINC; ++j) {
            float dx = xi - sp[j * 3 + 0];
            float dy = yi - sp[j * 3 + 1];
            float dz = zi - sp[j * 3 + 2];
            float d2 = (dx * dx + dy * dy) + dz * dz;  // contract(off): matches numpy order
            bool valid = (d2 < 36.0f) & (j != i);
            if (valid & (cnt < KK)) {
                o_src_ii[e0 + cnt] = (float)(goff + j);
                o_m_ii[e0 + cnt]   = 1.0f;
                o_d_ii[e0 + cnt]   = sqrtf(d2);
                cnt++;
            }
        }
        // Pad: smallest invalid candidate indices (j==i counts as invalid),
        // mask=0, dist=0. Divergent loop condition is fine (exec-mask handles).
        for (int j = 0; (j < NINC) && (cnt < KK); ++j) {
            float dx = xi - sp[j * 3 + 0];
            float dy = yi - sp[j * 3 + 1];
            float dz = zi - sp[j * 3 + 2];
            float d2 = (dx * dx + dy * dy) + dz * dz;
            bool valid = (d2 < 36.0f) & (j != i);
            if (!valid) {
                o_src_ii[e0 + cnt] = (float)(goff + j);
                o_m_ii[e0 + cnt]   = 0.0f;
                o_d_ii[e0 + cnt]   = 0.0f;
                cnt++;
            }
        }
    }

    // ---------------- in-out ----------------
    {
        int cnt = 0;
        for (int j = 0; j < NOUTC; ++j) {
            const int c = NINC + j;
            float dx = xi - sp[c * 3 + 0];
            float dy = yi - sp[c * 3 + 1];
            float dz = zi - sp[c * 3 + 2];
            float d2 = (dx * dx + dy * dy) + dz * dz;
            bool valid = (d2 < 36.0f);
            if (valid & (cnt < KK)) {
                o_src_io[e0 + cnt] = (float)(goff + NINC + j);
                o_m_io[e0 + cnt]   = 1.0f;
                o_d_io[e0 + cnt]   = sqrtf(d2);
                cnt++;
            }
        }
        for (int j = 0; (j < NOUTC) && (cnt < KK); ++j) {
            const int c = NINC + j;
            float dx = xi - sp[c * 3 + 0];
            float dy = yi - sp[c * 3 + 1];
            float dz = zi - sp[c * 3 + 2];
            float d2 = (dx * dx + dy * dy) + dz * dz;
            bool valid = (d2 < 36.0f);
            if (!valid) {
                o_src_io[e0 + cnt] = (float)(goff + NINC + j);
                o_m_io[e0 + cnt]   = 0.0f;
                o_d_io[e0 + cnt]   = 0.0f;
                cnt++;
            }
        }
    }
}

extern "C" void kernel_launch(void* const* d_in, const int* in_sizes, int n_in,
                              void* d_out, int out_size, void* d_ws, size_t ws_size,
                              hipStream_t stream) {
    const float* pos = (const float*)d_in[0];
    // d_in[1] = batch, d_in[2] = aux_ind — deterministic from index, unused.
    float* out = (float*)d_out;

    mo3e_neigh_kernel<<<dim3(BB), dim3(256), 0, stream>>>(pos, out);
}

// Round 2
// 126.533 us; speedup vs baseline: 2.4060x; 2.4060x over previous
//
#include <hip/hip_runtime.h>
#include <math.h>

// Mo3ENet neighbor selection: B=256, PER=1024, NIN=256, NOUT=768, K=32, R=6
// One wave (64 lanes) per target; ballot-based first-K-by-index compaction.
// Outputs (concatenated float32):
//   [0) src_ii | [E) tgt | [2E) m_ii | [3E) dist_ii |
//   [4E) src_io | [5E) tgt | [6E) m_io | [7E) dist_io

constexpr int BB    = 256;
constexpr int PERN  = 1024;
constexpr int NINC  = 256;
constexpr int NOUTC = 768;
constexpr int KK    = 32;
constexpr long EE   = (long)BB * NINC * KK;  // 2097152

__device__ __forceinline__ int prefix_lt(unsigned long long m) {
    // number of set bits in m at positions < this lane's id
    return __builtin_amdgcn_mbcnt_hi((unsigned)(m >> 32),
           __builtin_amdgcn_mbcnt_lo((unsigned)m, 0u));
}

__global__ __launch_bounds__(256) void mo3e_ballot_kernel(const float* __restrict__ pos,
                                                          float* __restrict__ out) {
#pragma clang fp contract(off)
    __shared__ float4 sp[PERN];  // 16 KB: (x,y,z,0) per point

    const int b      = blockIdx.x >> 6;        // 64 blocks per batch
    const int i_base = (blockIdx.x & 63) * 4;  // 4 targets per block (1/wave)
    const int tid    = threadIdx.x;
    const int w      = tid >> 6;
    const int l      = tid & 63;

    // Stage this batch's 1024 positions into LDS as float4.
    const float* gp = pos + (long)b * PERN * 3;
    for (int idx = tid; idx < PERN; idx += 256) {
        sp[idx] = make_float4(gp[idx * 3 + 0], gp[idx * 3 + 1], gp[idx * 3 + 2], 0.0f);
    }
    __syncthreads();

    const int i = i_base + w;  // target index in [0, NIN)
    const float4 p = sp[i];
    const float xi = p.x, yi = p.y, zi = p.z;

    const int  goff = b * PERN;
    const long e0   = ((long)(b * NINC + i)) * KK;

    float* __restrict__ o_src_ii = out;
    float* __restrict__ o_tgt_ii = out + EE;
    float* __restrict__ o_m_ii   = out + 2 * EE;
    float* __restrict__ o_d_ii   = out + 3 * EE;
    float* __restrict__ o_src_io = out + 4 * EE;
    float* __restrict__ o_tgt_io = out + 5 * EE;
    float* __restrict__ o_m_io   = out + 6 * EE;
    float* __restrict__ o_d_io   = out + 7 * EE;

    // Coalesced half-wave fill of both tgt rows.
    const float tv = (float)(goff + i);
    if (l < KK) {
        o_tgt_ii[e0 + l] = tv;
        o_tgt_io[e0 + l] = tv;
    }

    // ================= in-in (candidates j in [0, 256)) =================
    {
        int cnt = 0;
        for (int it = 0; it < NINC / 64; ++it) {
            const int j = it * 64 + l;
            const float4 q = sp[j];
            const float dx = xi - q.x, dy = yi - q.y, dz = zi - q.z;
            const float d2 = (dx * dx + dy * dy) + dz * dz;  // contract off
            const bool valid = (d2 < 36.0f) && (j != i);
            const unsigned long long ms = __ballot(valid);
            const int slot = cnt + prefix_lt(ms);
            if (valid && slot < KK) {
                o_src_ii[e0 + slot] = (float)(goff + j);
                o_d_ii[e0 + slot]   = sqrtf(d2);
            }
            cnt += __popcll(ms);
            cnt = __builtin_amdgcn_readfirstlane(cnt);
            if (cnt >= KK) break;
        }
        const int S0 = cnt < KK ? cnt : KK;
        // mask row + zero-fill padded dist slots (coalesced half-wave).
        if (l < KK) {
            o_m_ii[e0 + l] = (l < S0) ? 1.0f : 0.0f;
            if (l >= S0) o_d_ii[e0 + l] = 0.0f;
        }
        // pad src with smallest invalid candidate indices.
        if (S0 < KK) {
            int pc = S0;
            for (int it = 0; it < NINC / 64; ++it) {
                const int j = it * 64 + l;
                const float4 q = sp[j];
                const float dx = xi - q.x, dy = yi - q.y, dz = zi - q.z;
                const float d2 = (dx * dx + dy * dy) + dz * dz;
                const bool inv = !((d2 < 36.0f) && (j != i));
                const unsigned long long ms = __ballot(inv);
                const int slot = pc + prefix_lt(ms);
                if (inv && slot < KK) o_src_ii[e0 + slot] = (float)(goff + j);
                pc += __popcll(ms);
                pc = __builtin_amdgcn_readfirstlane(pc);
                if (pc >= KK) break;
            }
        }
    }

    // ================= in-out (candidates c in [256, 1024)) =================
    {
        int cnt = 0;
        for (int it = 0; it < NOUTC / 64; ++it) {
            const int c = NINC + it * 64 + l;
            const float4 q = sp[c];
            const float dx = xi - q.x, dy = yi - q.y, dz = zi - q.z;
            const float d2 = (dx * dx + dy * dy) + dz * dz;
            const bool valid = (d2 < 36.0f);
            const unsigned long long ms = __ballot(valid);
            const int slot = cnt + prefix_lt(ms);
            if (valid && slot < KK) {
                o_src_io[e0 + slot] = (float)(goff + c);
                o_d_io[e0 + slot]   = sqrtf(d2);
            }
            cnt += __popcll(ms);
            cnt = __builtin_amdgcn_readfirstlane(cnt);
            if (cnt >= KK) break;
        }
        const int S0 = cnt < KK ? cnt : KK;
        if (l < KK) {
            o_m_io[e0 + l] = (l < S0) ? 1.0f : 0.0f;
            if (l >= S0) o_d_io[e0 + l] = 0.0f;
        }
        if (S0 < KK) {
            int pc = S0;
            for (int it = 0; it < NOUTC / 64; ++it) {
                const int c = NINC + it * 64 + l;
                const float4 q = sp[c];
                const float dx = xi - q.x, dy = yi - q.y, dz = zi - q.z;
                const float d2 = (dx * dx + dy * dy) + dz * dz;
                const bool inv = !(d2 < 36.0f);
                const unsigned long long ms = __ballot(inv);
                const int slot = pc + prefix_lt(ms);
                if (inv && slot < KK) o_src_io[e0 + slot] = (float)(goff + c);
                pc += __popcll(ms);
                pc = __builtin_amdgcn_readfirstlane(pc);
                if (pc >= KK) break;
            }
        }
    }
}

extern "C" void kernel_launch(void* const* d_in, const int* in_sizes, int n_in,
                              void* d_out, int out_size, void* d_ws, size_t ws_size,
                              hipStream_t stream) {
    const float* pos = (const float*)d_in[0];
    float* out = (float*)d_out;

    // 64 blocks per batch x 256 batches; 4 waves/block = 1 target/wave.
    mo3e_ballot_kernel<<<dim3(BB * 64), dim3(256), 0, stream>>>(pos, out);
}

// Round 4
// 110.378 us; speedup vs baseline: 2.7581x; 1.1464x over previous
//
#include <hip/hip_runtime.h>
#include <math.h>

// Mo3ENet neighbor selection: B=256, PER=1024, NIN=256, NOUT=768, K=32, R=6
// One wave per target; ballot compaction; saved masks for pad slots.
// Outputs (concatenated float32):
//   [0) src_ii | [E) tgt | [2E) m_ii | [3E) dist_ii |
//   [4E) src_io | [5E) tgt | [6E) m_io | [7E) dist_io

constexpr int BB    = 256;
constexpr int PERN  = 1024;
constexpr int NINC  = 256;
constexpr int NOUTC = 768;
constexpr int KK    = 32;
constexpr long EE   = (long)BB * NINC * KK;  // 2097152

__device__ __forceinline__ int prefix_lt(unsigned long long m) {
    return __builtin_amdgcn_mbcnt_hi((unsigned)(m >> 32),
           __builtin_amdgcn_mbcnt_lo((unsigned)m, 0u));
}

// v_sqrt_f32 (~1 ulp) — stored-distance threshold is ~0.02, safe.
__device__ __forceinline__ float fast_sqrt(float x) {
    return __builtin_amdgcn_sqrtf(x);
}

__global__ __launch_bounds__(1024) void mo3e_kernel(const float* __restrict__ pos,
                                                    float* __restrict__ out) {
#pragma clang fp contract(off)
    __shared__ float4 sp[PERN];  // 16 KB

    const int b   = blockIdx.x >> 4;         // 16 blocks per batch
    const int tid = threadIdx.x;
    const int l   = tid & 63;
    // wave-uniform target index, forced scalar:
    const int i = __builtin_amdgcn_readfirstlane((blockIdx.x & 15) * 16 + (tid >> 6));

    // Stage batch positions into LDS (one point per thread).
    const float* gp = pos + (long)b * PERN * 3;
    sp[tid] = make_float4(gp[tid * 3 + 0], gp[tid * 3 + 1], gp[tid * 3 + 2], 0.0f);
    __syncthreads();

    const float4 p = sp[i];
    const float xi = p.x, yi = p.y, zi = p.z;

    const int  goff = b * PERN;
    const long e0   = ((long)(b * NINC + i)) * KK;  // scalar

    float* __restrict__ p_src_ii = out + e0;
    float* __restrict__ p_tgt_ii = out + EE + e0;
    float* __restrict__ p_m_ii   = out + 2 * EE + e0;
    float* __restrict__ p_d_ii   = out + 3 * EE + e0;
    float* __restrict__ p_src_io = out + 4 * EE + e0;
    float* __restrict__ p_tgt_io = out + 5 * EE + e0;
    float* __restrict__ p_m_io   = out + 6 * EE + e0;
    float* __restrict__ p_d_io   = out + 7 * EE + e0;

    const float fl = (float)l;
    const float tv = (float)(goff + i);
    if (l < KK) {
        p_tgt_ii[l] = tv;
        p_tgt_io[l] = tv;
    }

    // ================= in-in: candidates j in [0, 256) =================
    {
        unsigned long long masks[NINC / 64];
        int cnt = 0;
#pragma unroll
        for (int it = 0; it < NINC / 64; ++it) {
            const int j = it * 64 + l;
            const float4 q = sp[j];
            const float dx = xi - q.x, dy = yi - q.y, dz = zi - q.z;
            const float d2 = (dx * dx + dy * dy) + dz * dz;  // contract off
            unsigned long long ms = __ballot(d2 < 36.0f);
            if (it == (i >> 6)) ms &= ~(1ull << (i & 63));   // scalar self-exclusion
            masks[it] = ms;
            const int slot = cnt + prefix_lt(ms);
            const bool mine = (ms >> l) & 1ull;
            if (mine && slot < KK) {
                p_src_ii[slot] = (float)(goff + it * 64) + fl;
                p_d_ii[slot]   = fast_sqrt(d2);
            }
            cnt += __popcll(ms);
            if (cnt >= KK) break;
        }
        const int S0 = cnt < KK ? cnt : KK;
        if (l < KK) {
            p_m_ii[l] = (l < S0) ? 1.0f : 0.0f;
            if (l >= S0) p_d_ii[l] = 0.0f;
        }
        if (S0 < KK) {  // pad with smallest invalid indices (masks all defined)
            int pc = S0;
#pragma unroll
            for (int it = 0; it < NINC / 64; ++it) {
                const unsigned long long inv = ~masks[it];
                const int slot = pc + prefix_lt(inv);
                const bool mine = (inv >> l) & 1ull;
                if (mine && slot < KK) p_src_ii[slot] = (float)(goff + it * 64) + fl;
                pc += __popcll(inv);
                if (pc >= KK) break;
            }
        }
    }

    // ================= in-out: candidates c in [256, 1024) =================
    {
        unsigned long long masks[NOUTC / 64];
        int cnt = 0;
#pragma unroll
        for (int it = 0; it < NOUTC / 64; ++it) {
            const int c = NINC + it * 64 + l;
            const float4 q = sp[c];
            const float dx = xi - q.x, dy = yi - q.y, dz = zi - q.z;
            const float d2 = (dx * dx + dy * dy) + dz * dz;
            const unsigned long long ms = __ballot(d2 < 36.0f);
            masks[it] = ms;
            const int slot = cnt + prefix_lt(ms);
            const bool mine = (ms >> l) & 1ull;
            if (mine && slot < KK) {
                p_src_io[slot] = (float)(goff + NINC + it * 64) + fl;
                p_d_io[slot]   = fast_sqrt(d2);
            }
            cnt += __popcll(ms);
            if (cnt >= KK) break;
        }
        const int S0 = cnt < KK ? cnt : KK;
        if (l < KK) {
            p_m_io[l] = (l < S0) ? 1.0f : 0.0f;
            if (l >= S0) p_d_io[l] = 0.0f;
        }
        if (S0 < KK) {
            int pc = S0;
#pragma unroll
            for (int it = 0; it < NOUTC / 64; ++it) {
                const unsigned long long inv = ~masks[it];
                const int slot = pc + prefix_lt(inv);
                const bool mine = (inv >> l) & 1ull;
                if (mine && slot < KK) p_src_io[slot] = (float)(goff + NINC + it * 64) + fl;
                pc += __popcll(inv);
                if (pc >= KK) break;
            }
        }
    }
}

extern "C" void kernel_launch(void* const* d_in, const int* in_sizes, int n_in,
                              void* d_out, int out_size, void* d_ws, size_t ws_size,
                              hipStream_t stream) {
    const float* pos = (const float*)d_in[0];
    float* out = (float*)d_out;

    // 16 blocks/batch x 256 batches; 1024 threads = 16 waves = 16 targets/block.
    mo3e_kernel<<<dim3(BB * 16), dim3(1024), 0, stream>>>(pos, out);
}

// Round 5
// 103.795 us; speedup vs baseline: 2.9330x; 1.0634x over previous
//
#include <hip/hip_runtime.h>

// Mo3ENet neighbor selection: B=256, PER=1024, NIN=256, NOUT=768, K=32, R=6
// Phase 1: ballot scan pushes candidate indices into per-wave LDS slot rows.
// Epilogue: half-wave pull, 4 fully-coalesced wave-wide stores per target.
// Outputs (concatenated float32):
//   [0) src_ii | [E) tgt | [2E) m_ii | [3E) dist_ii |
//   [4E) src_io | [5E) tgt | [6E) m_io | [7E) dist_io

constexpr int BB    = 256;
constexpr int PERN  = 1024;
constexpr int NINC  = 256;
constexpr int NOUTC = 768;
constexpr int KK    = 32;
constexpr unsigned EE = 256u * 256u * 32u;  // 2097152 elements per array

__device__ __forceinline__ int prefix_lt(unsigned long long m) {
    return __builtin_amdgcn_mbcnt_hi((unsigned)(m >> 32),
           __builtin_amdgcn_mbcnt_lo((unsigned)m, 0u));
}

__global__ __launch_bounds__(1024) void mo3e_kernel(const float* __restrict__ pos,
                                                    float* __restrict__ out) {
#pragma clang fp contract(off)
    __shared__ float4 sp[PERN];        // 16 KB positions
    __shared__ int    slotbuf[16][64]; // 4 KB: per wave, [0..31]=ii slots, [32..63]=io slots

    const int b   = blockIdx.x >> 4;   // 16 blocks per batch
    const int tid = threadIdx.x;
    const int w   = tid >> 6;
    const int l   = tid & 63;
    const int i   = __builtin_amdgcn_readfirstlane((blockIdx.x & 15) * 16 + w);

    // Stage batch positions into LDS (one point per thread).
    const float* gp = pos + (size_t)b * PERN * 3;
    sp[tid] = make_float4(gp[tid * 3 + 0], gp[tid * 3 + 1], gp[tid * 3 + 2], 0.0f);
    __syncthreads();

    const float4 p = sp[i];
    const float xi = p.x, yi = p.y, zi = p.z;

    int* slots = slotbuf[w];

    // ================= phase 1: in-in scan (j in [0,256)) =================
    int S0ii;
    {
        unsigned long long masks[4];
        int cnt = 0;
#pragma unroll
        for (int it = 0; it < 4; ++it) {
            const int j = it * 64 + l;
            const float4 q = sp[j];
            const float dx = xi - q.x, dy = yi - q.y, dz = zi - q.z;
            const float d2 = (dx * dx + dy * dy) + dz * dz;  // contract off
            const bool valid = (d2 < 36.0f) && (j != i);
            const unsigned long long ms = __ballot(valid);
            masks[it] = ms;
            const int slot = cnt + prefix_lt(ms);
            if (valid && slot < KK) slots[slot] = j;
            cnt += __popcll(ms);
            if (cnt >= KK) break;  // masks beyond unused (pad only runs if cnt<KK)
        }
        S0ii = cnt < KK ? cnt : KK;
        if (S0ii < KK) {  // pad: smallest invalid indices (includes j==i)
            int pc = S0ii;
#pragma unroll
            for (int it = 0; it < 4; ++it) {
                const unsigned long long inv = ~masks[it];
                const int slot = pc + prefix_lt(inv);
                const bool mine = (inv >> l) & 1ull;
                if (mine && slot < KK) slots[slot] = it * 64 + l;
                pc += __popcll(inv);
                if (pc >= KK) break;
            }
        }
    }

    // ================= phase 1: in-out scan (c in [256,1024)) =================
    int S0io;
    {
        unsigned long long masks[12];
        int cnt = 0;
#pragma unroll
        for (int it = 0; it < 12; ++it) {
            const int c = NINC + it * 64 + l;
            const float4 q = sp[c];
            const float dx = xi - q.x, dy = yi - q.y, dz = zi - q.z;
            const float d2 = (dx * dx + dy * dy) + dz * dz;
            const bool valid = (d2 < 36.0f);
            const unsigned long long ms = __ballot(valid);
            masks[it] = ms;
            const int slot = cnt + prefix_lt(ms);
            if (valid && slot < KK) slots[KK + slot] = c;
            cnt += __popcll(ms);
            if (cnt >= KK) break;
        }
        S0io = cnt < KK ? cnt : KK;
        if (S0io < KK) {
            int pc = S0io;
#pragma unroll
            for (int it = 0; it < 12; ++it) {
                const unsigned long long inv = ~masks[it];
                const int slot = pc + prefix_lt(inv);
                const bool mine = (inv >> l) & 1ull;
                if (mine && slot < KK) slots[KK + slot] = NINC + it * 64 + l;
                pc += __popcll(inv);
                if (pc >= KK) break;
            }
        }
    }

    // ================= epilogue: half-wave pull, coalesced stores =================
    // lanes 0..31: ii row; lanes 32..63: io row.
    {
        const int h = l >> 5;          // 0 = ii, 1 = io
        const int k = l & 31;
        const int idx = slots[l];      // candidate index within batch [0,1024)
        const float4 q = sp[idx];
        const float dx = xi - q.x, dy = yi - q.y, dz = zi - q.z;
        const float d2 = (dx * dx + dy * dy) + dz * dz;  // same op order as reference

        const int S0 = h ? S0io : S0ii;
        const bool mv = k < S0;
        const float dist = mv ? __builtin_amdgcn_sqrtf(d2) : 0.0f;

        const int goff = b * PERN;
        const unsigned e0  = (unsigned)(b * NINC + i) * KK;
        const unsigned off = (h ? 4u * EE : 0u) + e0 + (unsigned)k;

        out[off]           = (float)(goff + idx);  // src (io idx already includes +NIN)
        out[off + EE]      = (float)(goff + i);    // tgt
        out[off + 2u * EE] = mv ? 1.0f : 0.0f;     // mask
        out[off + 3u * EE] = dist;                 // dist
    }
}

extern "C" void kernel_launch(void* const* d_in, const int* in_sizes, int n_in,
                              void* d_out, int out_size, void* d_ws, size_t ws_size,
                              hipStream_t stream) {
    const float* pos = (const float*)d_in[0];
    float* out = (float*)d_out;

    // 16 blocks/batch x 256 batches; 1024 threads = 16 waves = 16 targets/block.
    mo3e_kernel<<<dim3(BB * 16), dim3(1024), 0, stream>>>(pos, out);
}